// Round 1
// baseline (14.070 us; speedup 1.0000x reference)
//
#include <hip/hip_runtime.h>

namespace {
constexpr int IC = 8, IH = 28, IW = 28;
constexpr int OC = 16, KH = 3, KW = 3;
constexpr int OH = 28, OW = 28;
constexpr int BATCH = 64;
constexpr int XIN  = IC * IH * IW;   // 6272
constexpr int XOUT = OC * OH * OW;   // 12544
constexpr int PIH = IH + 2, PIW = IW + 2;   // 30x30 zero-padded image
constexpr int PSZ = IC * PIH * PIW;  // 7200 floats = 28.8 KB
constexpr int KSZ = IC * KH * KW;    // 72 taps per output channel
constexpr int THREADS = 256;
}

// weight is the Toeplitz expansion of a 16x8x3x3 conv kernel (stride 1, pad 1).
// kernel[oc,ic,ky,kx] lives at weight[row, col] with
//   row = oc*784 + 14*28 + 14   (interior output point oy=ox=14)
//   col = ic*784 + (13+ky)*28 + (13+kx)
// so we read 72 taps per block instead of streaming 314 MB of mostly-zeros.
__global__ __launch_bounds__(THREADS) void conv2d_toeplitz_kernel(
    const float* __restrict__ x, const float* __restrict__ w,
    const float* __restrict__ bias, float* __restrict__ out)
{
    __shared__ float xs[PSZ];
    __shared__ float ks[KSZ];
    __shared__ float bs;

    const int tid = threadIdx.x;
    const int b   = blockIdx.x >> 4;   // 64 batches
    const int oc  = blockIdx.x & 15;   // 16 output channels

    // zero the padded LDS image (halo must be 0)
    for (int i = tid; i < PSZ; i += THREADS) xs[i] = 0.0f;
    __syncthreads();

    // stage x[b] into the padded interior (coalesced global reads)
    const float* xb = x + b * XIN;
    for (int i = tid; i < XIN; i += THREADS) {
        int ic = i / (IH * IW);
        int r  = i - ic * (IH * IW);
        int iy = r / IW;
        int ix = r - iy * IW;
        xs[ic * (PIH * PIW) + (iy + 1) * PIW + (ix + 1)] = xb[i];
    }
    // extract this oc's 72 kernel taps from the Toeplitz matrix
    if (tid < KSZ) {
        int ic = tid / (KH * KW);
        int kr = tid - ic * (KH * KW);
        int ky = kr / KW;
        int kx = kr - ky * KW;
        int row = oc * (OH * OW) + 14 * OW + 14;
        int col = ic * (IH * IW) + (13 + ky) * IW + (13 + kx);
        ks[tid] = w[(long)row * XIN + col];
    }
    // bias is jnp.repeat(per-channel, 784): one scalar per oc
    if (tid == KSZ) bs = bias[oc * (OH * OW)];
    __syncthreads();

    // 196 threads x 4 consecutive outputs (28 = 7 groups of 4: never crosses a row)
    if (tid < 196) {
        const int oy = tid / 7;
        const int ox = (tid - oy * 7) * 4;
        const float b0 = bs;
        float a0 = b0, a1 = b0, a2 = b0, a3 = b0;
        #pragma unroll
        for (int ic = 0; ic < IC; ++ic) {
            #pragma unroll
            for (int ky = 0; ky < KH; ++ky) {
                const float* xr = &xs[ic * (PIH * PIW) + (oy + ky) * PIW + ox];
                const float x0 = xr[0], x1 = xr[1], x2 = xr[2];
                const float x3 = xr[3], x4 = xr[4], x5 = xr[5];
                const float* kr = &ks[ic * (KH * KW) + ky * KW];
                const float k0 = kr[0], k1 = kr[1], k2 = kr[2];
                a0 = fmaf(x2, k2, fmaf(x1, k1, fmaf(x0, k0, a0)));
                a1 = fmaf(x3, k2, fmaf(x2, k1, fmaf(x1, k0, a1)));
                a2 = fmaf(x4, k2, fmaf(x3, k1, fmaf(x2, k0, a2)));
                a3 = fmaf(x5, k2, fmaf(x4, k1, fmaf(x3, k0, a3)));
            }
        }
        // out index: b*12544 + oc*784 + oy*28 + ox; ox % 4 == 0 -> 16B aligned
        float4 v = make_float4(a0, a1, a2, a3);
        float4* op = reinterpret_cast<float4*>(
            out + (long)b * XOUT + oc * (OH * OW) + oy * OW + ox);
        *op = v;
    }
}

extern "C" void kernel_launch(void* const* d_in, const int* in_sizes, int n_in,
                              void* d_out, int out_size, void* d_ws, size_t ws_size,
                              hipStream_t stream) {
    const float* x    = (const float*)d_in[0];   // enc_x  [64, 6272] f32
    const float* w    = (const float*)d_in[1];   // weight [12544, 6272] f32 (Toeplitz)
    const float* bias = (const float*)d_in[2];   // bias   [12544] f32 (repeat per oc)
    float* out = (float*)d_out;                  // [64, 12544] f32

    conv2d_toeplitz_kernel<<<dim3(BATCH * OC), THREADS, 0, stream>>>(x, w, bias, out);
}

// Round 2
// 13.067 us; speedup vs baseline: 1.0768x; 1.0768x over previous
//
#include <hip/hip_runtime.h>

namespace {
constexpr int IC = 8, IH = 28, IW = 28;
constexpr int OC = 16, KH = 3, KW = 3;
constexpr int OH = 28, OW = 28;
constexpr int BATCH = 64;
constexpr int XIN  = IC * IH * IW;   // 6272
constexpr int XOUT = OC * OH * OW;   // 12544
constexpr int PIH = IH + 2, PIW = IW + 2;   // 30x30 zero-padded image
constexpr int CSZ = PIH * PIW;       // 900 floats per channel
constexpr int PSZ = IC * CSZ;        // 7200 floats = 28.8 KB
constexpr int KSZ = IC * KH * KW;    // 72 taps per output channel
constexpr int THREADS = 256;
constexpr int NV4 = XIN / 4;         // 1568 float4 per image
}

// weight is the Toeplitz expansion of a 16x8x3x3 conv kernel (stride 1, pad 1).
// kernel[oc,ic,ky,kx] = weight[oc*784 + 14*28+14, ic*784 + (13+ky)*28 + (13+kx)]
// (interior output point oy=ox=14). 72 taps per block instead of 314 MB GEMM.
__global__ __launch_bounds__(THREADS) void conv2d_toeplitz_kernel(
    const float* __restrict__ x, const float* __restrict__ w,
    const float* __restrict__ bias, float* __restrict__ out)
{
    __shared__ float xs[PSZ];
    __shared__ float ks[KSZ];
    __shared__ float bs;

    const int tid = threadIdx.x;
    const int b   = blockIdx.x >> 4;   // 64 batches
    const int oc  = blockIdx.x & 15;   // 16 output channels

    // ---- issue ALL global loads first (latency hides under halo zeroing) ----
    // tap / bias load (one predicated load, block-uniform address set)
    float tv = 0.0f;
    if (tid < KSZ + 1) {
        long a;
        if (tid < KSZ) {
            int ic = tid / (KH * KW);
            int kr = tid - ic * (KH * KW);
            int ky = kr / KW;
            int kx = kr - ky * KW;
            int row = oc * (OH * OW) + 14 * OW + 14;
            int col = ic * (IH * IW) + (13 + ky) * IW + (13 + kx);
            a = (long)row * XIN + col;
            tv = w[a];
        } else {
            tv = bias[oc * (OH * OW)];
        }
    }
    // staged image as float4 (rows are 7 aligned groups of 4, never cross rows)
    const float4* xb4 = reinterpret_cast<const float4*>(x + b * XIN);
    float4 v[7];
    #pragma unroll
    for (int k = 0; k < 7; ++k) {
        int i = tid + k * THREADS;
        if (i < NV4) v[k] = xb4[i];
    }

    // ---- zero ONLY the halo (disjoint from interior: no barrier needed) ----
    // 116 halo cells per channel: top row 30, bottom row 30, left 28, right 28
    for (int i = tid; i < IC * 116; i += THREADS) {
        int ic = i / 116;
        int h  = i - ic * 116;
        int cell;
        if (h < 60)      cell = (h < 30) ? h : (29 * PIW + (h - 30));
        else if (h < 88) cell = (h - 59) * PIW;           // left col, rows 1..28
        else             cell = (h - 87) * PIW + (PIW-1); // right col, rows 1..28
        xs[ic * CSZ + cell] = 0.0f;
    }

    // ---- write staged data into the padded interior ----
    #pragma unroll
    for (int k = 0; k < 7; ++k) {
        int i = tid + k * THREADS;
        if (i < NV4) {
            int ic  = i / 196;            // 196 float4 per channel
            int r   = i - ic * 196;
            int row = r / 7;
            int cf  = (r - row * 7) * 4;
            int dst = ic * CSZ + (row + 1) * PIW + (cf + 1);
            xs[dst]     = v[k].x;
            xs[dst + 1] = v[k].y;
            xs[dst + 2] = v[k].z;
            xs[dst + 3] = v[k].w;
        }
    }
    if (tid < KSZ) ks[tid] = tv;
    if (tid == KSZ) bs = tv;

    __syncthreads();   // the ONLY barrier

    // ---- 196 threads x 4 consecutive outputs (28 = 7 groups of 4) ----
    if (tid < 196) {
        const int oy = tid / 7;
        const int ox = (tid - oy * 7) * 4;
        const float b0 = bs;
        float a0 = b0, a1 = b0, a2 = b0, a3 = b0;
        #pragma unroll
        for (int ic = 0; ic < IC; ++ic) {
            #pragma unroll
            for (int ky = 0; ky < KH; ++ky) {
                const float* xr = &xs[ic * CSZ + (oy + ky) * PIW + ox];
                const float x0 = xr[0], x1 = xr[1], x2 = xr[2];
                const float x3 = xr[3], x4 = xr[4], x5 = xr[5];
                const float* kr = &ks[ic * (KH * KW) + ky * KW];
                const float k0 = kr[0], k1 = kr[1], k2 = kr[2];
                a0 = fmaf(x2, k2, fmaf(x1, k1, fmaf(x0, k0, a0)));
                a1 = fmaf(x3, k2, fmaf(x2, k1, fmaf(x1, k0, a1)));
                a2 = fmaf(x4, k2, fmaf(x3, k1, fmaf(x2, k0, a2)));
                a3 = fmaf(x5, k2, fmaf(x4, k1, fmaf(x3, k0, a3)));
            }
        }
        // out index: b*12544 + oc*784 + oy*28 + ox; ox % 4 == 0 -> 16B aligned
        float4* op = reinterpret_cast<float4*>(
            out + (long)b * XOUT + oc * (OH * OW) + oy * OW + ox);
        *op = make_float4(a0, a1, a2, a3);
    }
}

extern "C" void kernel_launch(void* const* d_in, const int* in_sizes, int n_in,
                              void* d_out, int out_size, void* d_ws, size_t ws_size,
                              hipStream_t stream) {
    const float* x    = (const float*)d_in[0];   // enc_x  [64, 6272] f32
    const float* w    = (const float*)d_in[1];   // weight [12544, 6272] f32 (Toeplitz)
    const float* bias = (const float*)d_in[2];   // bias   [12544] f32 (repeat per oc)
    float* out = (float*)d_out;                  // [64, 12544] f32

    conv2d_toeplitz_kernel<<<dim3(BATCH * OC), THREADS, 0, stream>>>(x, w, bias, out);
}